// Round 22
// baseline (46.393 us; speedup 1.0000x reference)
//
#include <hip/hip_runtime.h>
#include <hip/hip_bf16.h>

// N=8192 points, k=8 kNN -> mean |plane distance|.
// R22: dynamic per-lane threshold. Stage 0 inserts ALL its accs (live regs,
// static idx) establishing each lane's exact acc-space top-8; stages 1-7 mask
// against the lane's own evolving best[7] (bkT) -- no sampling pass, no Tm
// array, no margins. Keys are acc-space (R20/21 criterion, absmax 0); mask is
// a provable superset of acc-space top-8 updates. Indices exact; finalize
// plane distances exact f32.
//   d2(r,c) via 16x16x32 bf16 MFMA, hi/lo split over 13 K-slots (validated
//   R10-R21).
#define NPTS 8192
#define KNN 8
#define RPB 16            // rows per block
#define STAGES 8
#define SCOLS 1024        // cols per stage; wave band = 128 cols = 8 MFMA

typedef __attribute__((ext_vector_type(8))) short bf16x8;
typedef __attribute__((ext_vector_type(4))) float f32x4;

__device__ __forceinline__ unsigned int bf16rne(float v) {
    unsigned int u = __float_as_uint(v);
    return (u + 0x7FFFu + ((u >> 16) & 1u)) >> 16;
}
__device__ __forceinline__ float bf2f(unsigned int h) { return __uint_as_float(h << 16); }

__device__ __forceinline__ void insert8(unsigned int (&best)[KNN], unsigned int key) {
#pragma unroll
    for (int t = 0; t < KNN; ++t) {
        const unsigned int lo = min(best[t], key);
        key = max(best[t], key);
        best[t] = lo;
    }
}

// Pure pack: pts + candidate frags + row frags; zero out. 8192 threads.
__global__ __launch_bounds__(256) void pack_kernel(const float* __restrict__ means,
                                                   float4* __restrict__ pts,
                                                   uint4* __restrict__ cf0,
                                                   uint4* __restrict__ cf1,
                                                   uint4* __restrict__ rf0,
                                                   uint4* __restrict__ rf1,
                                                   float* __restrict__ out) {
    const int i = blockIdx.x * 256 + threadIdx.x;
    if (i == 0) out[0] = 0.0f;
    const float x = means[3 * i + 0];
    const float y = means[3 * i + 1];
    const float z = means[3 * i + 2];
    const float sq = x * x + y * y + z * z;
    pts[i] = make_float4(x, y, z, sq);
    const unsigned int hx = bf16rne(x), lx = bf16rne(x - bf2f(hx));
    const unsigned int hy = bf16rne(y), ly = bf16rne(y - bf2f(hy));
    const unsigned int hz = bf16rne(z), lz = bf16rne(z - bf2f(hz));
    const unsigned int hs = bf16rne(sq), ls = bf16rne(sq - bf2f(hs));
    cf0[i] = make_uint4(hx | (lx << 16), hx | (hy << 16),
                        ly | (hy << 16), hz | (lz << 16));
    cf1[i] = make_uint4(hz | (hs << 16), ls | (0x3F80u << 16), 0x3F80u, 0u);
    const float ax = -2.0f * x, ay = -2.0f * y, az = -2.0f * z;
    const unsigned int hax = bf16rne(ax), lax = bf16rne(ax - bf2f(hax));
    const unsigned int hay = bf16rne(ay), lay = bf16rne(ay - bf2f(hay));
    const unsigned int haz = bf16rne(az), laz = bf16rne(az - bf2f(haz));
    const unsigned int hsr = bf16rne(sq), lsr = bf16rne(sq - bf2f(hsr));
    rf0[i] = make_uint4(hax | (hax << 16), lax | (hay << 16),
                        hay | (lay << 16), haz | (haz << 16));
    rf1[i] = make_uint4(laz | (0x3F80u << 16), 0x3F80u | (hsr << 16), lsr, 0u);
}

// 512 blocks x 512 threads (8 waves); block owns 16 rows; barrier-free main
// loop; dynamic per-lane threshold from the lane's own best[7].
__global__ __launch_bounds__(512) void mfma_knn(const uint4* __restrict__ cf0,
                                                const uint4* __restrict__ cf1,
                                                const uint4* __restrict__ rf0,
                                                const uint4* __restrict__ rf1,
                                                const float4* __restrict__ pts,
                                                const float* __restrict__ normals,
                                                float* __restrict__ out) {
    __shared__ unsigned int lds_acc[8][16][64];   // 32 KB; [wave][t][lane]
    __shared__ unsigned int km[8][RPB][KNN + 1];
    const int tid = threadIdx.x;
    const int l = tid & 63;
    const int wv = __builtin_amdgcn_readfirstlane(tid >> 6);
    const int R = l & 15;     // my query row
    const int g = l >> 4;     // candidate sub-slice
    const int arow = blockIdx.x * RPB + R;

    const float4 mp = pts[arow];

    // B fragment: my row; lanes g>=2 supply zero (their K-slots unused)
    uint4 bu = make_uint4(0u, 0u, 0u, 0u);
    if (g == 0) bu = rf0[arow];
    else if (g == 1) bu = rf1[arow];
    union { uint4 u; bf16x8 v; } Bf; Bf.u = bu;
    const f32x4 zero = {0.0f, 0.0f, 0.0f, 0.0f};

    // A-fragments from L2; g>=2 lanes duplicate g0's address (broadcast, free)
    const uint4* __restrict__ asel = (g == 1) ? cf1 : cf0;

    unsigned int best[KNN];
#pragma unroll
    for (int s = 0; s < KNN; ++s) best[s] = ~0u;

    // ---- stage 0: full insert of all 32 per-lane accs (no mask, no spill) ----
    {
        const int lbase = wv * 128 + R;
#pragma unroll
        for (int mt = 0; mt < 8; ++mt) {
            union { uint4 u; bf16x8 v; } Af;
            Af.u = asel[lbase + mt * 16];
            const f32x4 acc = __builtin_amdgcn_mfma_f32_16x16x32_bf16(Af.v, Bf.v, zero, 0, 0, 0);
#pragma unroll
            for (int r = 0; r < 4; ++r) {
                const float av = fmaxf(acc[r], 0.0f);
                const int col = wv * 128 + mt * 16 + g * 4 + r;   // static
                unsigned int key = (__float_as_uint(av) & 0xFFFFE000u) | (unsigned int)col;
                key = (col == arow) ? ~0u : key;                  // drop self
                insert8(best, key);
            }
        }
    }
    // dynamic threshold: any acc whose truncation could beat best[7]
    float bkT = __uint_as_float(best[7] | 0x1FFFu);

    // ---- stages 1..7: mask vs bkT, spill accs, per-half-stage decode ----
#pragma unroll 1
    for (int s = 1; s < STAGES; ++s) {
        const int lbase = s * SCOLS + wv * 128 + R;
        const int cbase = s * SCOLS + wv * 128;
#pragma unroll
        for (int h = 0; h < 2; ++h) {
            unsigned int m = 0u;
#pragma unroll
            for (int mt4 = 0; mt4 < 4; ++mt4) {
                const int mt = h * 4 + mt4;
                union { uint4 u; bf16x8 v; } Af;
                Af.u = asel[lbase + mt * 16];
                const f32x4 acc = __builtin_amdgcn_mfma_f32_16x16x32_bf16(Af.v, Bf.v, zero, 0, 0, 0);
                lds_acc[wv][mt4 * 4 + 0][l] = __float_as_uint(acc[0]);
                lds_acc[wv][mt4 * 4 + 1][l] = __float_as_uint(acc[1]);
                lds_acc[wv][mt4 * 4 + 2][l] = __float_as_uint(acc[2]);
                lds_acc[wv][mt4 * 4 + 3][l] = __float_as_uint(acc[3]);
                m = m + m + ((acc[0] <= bkT) ? 1u : 0u);
                m = m + m + ((acc[1] <= bkT) ? 1u : 0u);
                m = m + m + ((acc[2] <= bkT) ? 1u : 0u);
                m = m + m + ((acc[3] <= bkT) ? 1u : 0u);
            }
            // decode survivors (acc from LDS; own-wave data, program order ok)
            while (m) {
                const int b = __ffs(m) - 1;
                m &= m - 1;
                const int t = 15 - b;                 // t = mt4*4 + r
                const float av = fmaxf(__uint_as_float(lds_acc[wv][t][l]), 0.0f);
                const int col = cbase + (h * 4 + (t >> 2)) * 16 + g * 4 + (t & 3);
                unsigned int key = (__float_as_uint(av) & 0xFFFFE000u) | (unsigned int)col;
                key = (col == arow) ? ~0u : key;      // drop self
                insert8(best, key);
            }
            bkT = __uint_as_float(best[7] | 0x1FFFu);  // tighten once per half
        }
    }

    // merge the 4 g-lanes sharing this row within the wave
#pragma unroll
    for (int st = 16; st <= 32; st <<= 1) {
        unsigned int tk[KNN];
#pragma unroll
        for (int s = 0; s < KNN; ++s) tk[s] = __shfl_xor(best[s], st);
#pragma unroll
        for (int s = 0; s < KNN; ++s) insert8(best, tk[s]);
    }
    // merge across 8 waves (LDS tree)
    if (l < RPB) {
#pragma unroll
        for (int s = 0; s < KNN; ++s) km[wv][l][s] = best[s];
    }
    for (int st = 1; st < 8; st <<= 1) {
        __syncthreads();
        if (((wv & (2 * st - 1)) == 0) && l < RPB) {
#pragma unroll
            for (int s = 0; s < KNN; ++s) insert8(best, km[wv + st][l][s]);
#pragma unroll
            for (int s = 0; s < KNN; ++s) km[wv][l][s] = best[s];
        }
    }

    // finalize: wave 0, lanes 0..15 hold the 16 rows (indices exact)
    if (wv == 0) {
        float sum = 0.0f;
        if (l < RPB) {
            const float nx = normals[3 * arow + 0];
            const float ny = normals[3 * arow + 1];
            const float nz = normals[3 * arow + 2];
#pragma unroll
            for (int s = 0; s < KNN; ++s) {
                const int nbr = (int)(best[s] & 0x1FFFu);
                const float4 q = pts[nbr];
                sum += fabsf((q.x - mp.x) * nx + (q.y - mp.y) * ny + (q.z - mp.z) * nz);
            }
        }
#pragma unroll
        for (int off = 8; off > 0; off >>= 1) sum += __shfl_down(sum, off);
        if (l == 0) atomicAdd(out, sum * (1.0f / ((float)NPTS * (float)KNN)));
    }
}

extern "C" void kernel_launch(void* const* d_in, const int* in_sizes, int n_in,
                              void* d_out, int out_size, void* d_ws, size_t ws_size,
                              hipStream_t stream) {
    const float* means = (const float*)d_in[0];
    const float* normals = (const float*)d_in[1];
    float* out = (float*)d_out;
    char* ws = (char*)d_ws;
    uint4* cf0 = (uint4*)ws;                        // 128 KB
    uint4* cf1 = (uint4*)(ws + 131072);             // 128 KB
    uint4* rf0 = (uint4*)(ws + 262144);             // 128 KB
    uint4* rf1 = (uint4*)(ws + 393216);             // 128 KB
    float4* pts = (float4*)(ws + 524288);           // 128 KB

    pack_kernel<<<NPTS / 256, 256, 0, stream>>>(means, pts, cf0, cf1, rf0, rf1, out);
    mfma_knn<<<NPTS / RPB, 512, 0, stream>>>(cf0, cf1, rf0, rf1, pts, normals, out);
}

// Round 23
// 34.995 us; speedup vs baseline: 1.3257x; 1.3257x over previous
//
#include <hip/hip_runtime.h>
#include <hip/hip_bf16.h>

// N=8192 points, k=8 exact kNN -> mean |plane distance|.
// R23 = R18 verbatim (session-best, 34.95 us): prep packs pts + candidate
// frags (cf0/cf1) + row frags (rf0/rf1) + per-point thresholds; mfma_knn is a
// barrier-free MFMA filter reading A-frags from L2 with a register-pipelined
// stream, survivors re-scored exactly in f32.
//   d2(r,c) = sq_r + sq_c - 2 p_r.q_c, hi/lo bf16 split over 13 K-slots
//   (absmax 0 across R10-R22); margin 0.02+2e-3*T keeps the filter a
//   guaranteed superset; survivors re-scored exactly in f32 -> selection
//   exact (19-bit d2 | 13-bit idx keys, unique, jax tie-break).
#define NPTS 8192
#define KNN 8
#define RPB 16            // rows per mfma block
#define STAGES 8
#define SCOLS 1024        // cols per stage; wave band = 128 cols = 8 MFMA

typedef __attribute__((ext_vector_type(8))) short bf16x8;
typedef __attribute__((ext_vector_type(4))) float f32x4;

__device__ __forceinline__ unsigned int bf16rne(float v) {
    unsigned int u = __float_as_uint(v);
    return (u + 0x7FFFu + ((u >> 16) & 1u)) >> 16;
}
__device__ __forceinline__ float bf2f(unsigned int h) { return __uint_as_float(h << 16); }

__device__ __forceinline__ void insert8(unsigned int (&best)[KNN], unsigned int key) {
#pragma unroll
    for (int t = 0; t < KNN; ++t) {
        const unsigned int lo = min(best[t], key);
        key = max(best[t], key);
        best[t] = lo;
    }
}
__device__ __forceinline__ void insert4(unsigned int (&b)[4], unsigned int key) {
#pragma unroll
    for (int t = 0; t < 4; ++t) {
        const unsigned int lo = min(b[t], key);
        key = max(b[t], key);
        b[t] = lo;
    }
}

// 256 blocks x 512 threads; 32 points/block; 16 classes x 32 samples each.
// Sample set = {16j : j=0..511} (validated R12-R18).
__global__ __launch_bounds__(512) void prep_thresh(const float* __restrict__ means,
                                                   float4* __restrict__ pts,
                                                   uint4* __restrict__ cf0,
                                                   uint4* __restrict__ cf1,
                                                   uint4* __restrict__ rf0,
                                                   uint4* __restrict__ rf1,
                                                   float* __restrict__ Tm_arr,
                                                   float* __restrict__ out) {
    __shared__ unsigned int lds4[16][32][5];   // per-class top-4 (+pad)
    __shared__ unsigned int lds8[4][32][8];    // round-1 top-8
    const int tid = threadIdx.x;
    const int pl = tid & 31;
    const int cls = tid >> 5;                  // 16 sample classes
    const int pt = blockIdx.x * 32 + pl;
    if (blockIdx.x == 0 && tid == 0) out[0] = 0.0f;

    const float x = means[3 * pt + 0];
    const float y = means[3 * pt + 1];
    const float z = means[3 * pt + 2];
    const float sq = x * x + y * y + z * z;
    if (cls == 0) {
        pts[pt] = make_float4(x, y, z, sq);
        const unsigned int hx = bf16rne(x), lx = bf16rne(x - bf2f(hx));
        const unsigned int hy = bf16rne(y), ly = bf16rne(y - bf2f(hy));
        const unsigned int hz = bf16rne(z), lz = bf16rne(z - bf2f(hz));
        const unsigned int hs = bf16rne(sq), ls = bf16rne(sq - bf2f(hs));
        cf0[pt] = make_uint4(hx | (lx << 16), hx | (hy << 16),
                             ly | (hy << 16), hz | (lz << 16));
        cf1[pt] = make_uint4(hz | (hs << 16), ls | (0x3F80u << 16), 0x3F80u, 0u);
        const float ax = -2.0f * x, ay = -2.0f * y, az = -2.0f * z;
        const unsigned int hax = bf16rne(ax), lax = bf16rne(ax - bf2f(hax));
        const unsigned int hay = bf16rne(ay), lay = bf16rne(ay - bf2f(hay));
        const unsigned int haz = bf16rne(az), laz = bf16rne(az - bf2f(haz));
        const unsigned int hsr = bf16rne(sq), lsr = bf16rne(sq - bf2f(hsr));
        rf0[pt] = make_uint4(hax | (hax << 16), lax | (hay << 16),
                             hay | (lay << 16), haz | (haz << 16));
        rf1[pt] = make_uint4(laz | (0x3F80u << 16), 0x3F80u | (hsr << 16), lsr, 0u);
    }

    // 32 samples/thread at cols 16*(cls + 16*m)
    const float mx2 = -2.0f * x, my2 = -2.0f * y, mz2 = -2.0f * z;
    unsigned int b4[4] = {~0u, ~0u, ~0u, ~0u};
#pragma unroll 4
    for (int m = 0; m < 32; ++m) {
        const int col = 16 * (cls + 16 * m);
        const float qx = means[3 * col + 0];
        const float qy = means[3 * col + 1];
        const float qz = means[3 * col + 2];
        const float qsq = qx * qx + qy * qy + qz * qz;
        const float d2 = fmaxf(fmaf(mx2, qx, fmaf(my2, qy, fmaf(mz2, qz, sq + qsq))), 0.0f);
        unsigned int key = (__float_as_uint(d2) & 0xFFFFE000u) | (unsigned int)col;
        key = (col == pt) ? ~0u : key;
        insert4(b4, key);   // per-thread top-4 (subset pruning keeps T an upper bound)
    }
#pragma unroll
    for (int j = 0; j < 4; ++j) lds4[cls][pl][j] = b4[j];
    __syncthreads();
    if (tid < 128) {        // round 1: 4 classes (16 keys) -> top-8
        const int p2 = tid & 31, q = tid >> 5;
        unsigned int bb[KNN];
#pragma unroll
        for (int s = 0; s < KNN; ++s) bb[s] = ~0u;
        for (int c = q * 4; c < q * 4 + 4; ++c)
#pragma unroll
            for (int j = 0; j < 4; ++j) insert8(bb, lds4[c][p2][j]);
#pragma unroll
        for (int s = 0; s < KNN; ++s) lds8[q][p2][s] = bb[s];
    }
    __syncthreads();
    if (tid < 32) {         // round 2: 32 keys -> top-8 -> T
        unsigned int bb[KNN];
#pragma unroll
        for (int s = 0; s < KNN; ++s) bb[s] = ~0u;
        for (int q = 0; q < 4; ++q)
#pragma unroll
            for (int s = 0; s < KNN; ++s) insert8(bb, lds8[q][tid][s]);
        const float Tf = __uint_as_float(bb[7] & 0xFFFFE000u);
        Tm_arr[blockIdx.x * 32 + tid] = Tf + 0.02f + 2e-3f * Tf;  // trunc + mfma error
    }
}

// 512 blocks x 512 threads; block owns 16 rows; barrier-free main loop with
// register-double-buffered A-frag stream.
__global__ __launch_bounds__(512, 4) void mfma_knn(const uint4* __restrict__ cf0,
                                                   const uint4* __restrict__ cf1,
                                                   const uint4* __restrict__ rf0,
                                                   const uint4* __restrict__ rf1,
                                                   const float4* __restrict__ pts,
                                                   const float* __restrict__ Tm_arr,
                                                   const float* __restrict__ normals,
                                                   float* __restrict__ out) {
    __shared__ unsigned int km[8][RPB][KNN + 1];
    const int tid = threadIdx.x;
    const int l = tid & 63;
    const int wv = __builtin_amdgcn_readfirstlane(tid >> 6);
    const int R = l & 15;     // my query row
    const int g = l >> 4;     // k-group / candidate sub-slice
    const int arow = blockIdx.x * RPB + R;

    const float4 mp = pts[arow];
    const float ax = -2.0f * mp.x, ay = -2.0f * mp.y, az = -2.0f * mp.z;
    const float sq = mp.w;
    const float Tm = Tm_arr[arow];

    // B fragment: my row; lanes g>=2 supply zero (their K-slots unused)
    uint4 bu = make_uint4(0u, 0u, 0u, 0u);
    if (g == 0) bu = rf0[arow];
    else if (g == 1) bu = rf1[arow];
    union { uint4 u; bf16x8 v; } Bf; Bf.u = bu;
    const f32x4 zero = {0.0f, 0.0f, 0.0f, 0.0f};

    // A-fragments straight from L2; g>=2 lanes duplicate g0's address (broadcast)
    const uint4* __restrict__ asel = (g == 1) ? cf1 : cf0;
    const int lofs = wv * 128 + R;

    unsigned int best[KNN];
#pragma unroll
    for (int s = 0; s < KNN; ++s) best[s] = ~0u;

    // prologue: stage 0 fragments
    uint4 c0 = asel[lofs + 0],   c1 = asel[lofs + 16],  c2 = asel[lofs + 32],
          c3 = asel[lofs + 48],  c4 = asel[lofs + 64],  c5 = asel[lofs + 80],
          c6 = asel[lofs + 96],  c7 = asel[lofs + 112];

#define KSTEP(CC)                                                                     \
    {                                                                                 \
        union { uint4 u; bf16x8 v; } Af; Af.u = (CC);                                 \
        const f32x4 acc = __builtin_amdgcn_mfma_f32_16x16x32_bf16(Af.v, Bf.v, zero, 0, 0, 0); \
        m = m + m + ((acc[0] <= Tm) ? 1u : 0u);                                       \
        m = m + m + ((acc[1] <= Tm) ? 1u : 0u);                                       \
        m = m + m + ((acc[2] <= Tm) ? 1u : 0u);                                       \
        m = m + m + ((acc[3] <= Tm) ? 1u : 0u);                                       \
    }

#pragma unroll 1
    for (int s = 0; s < STAGES; ++s) {
        // issue next-stage prefetch (wraps to stage 0 on last iter; discarded)
        const int nofs = ((s + 1) & (STAGES - 1)) * SCOLS + lofs;
        const uint4 n0 = asel[nofs + 0],   n1 = asel[nofs + 16];
        const uint4 n2 = asel[nofs + 32],  n3 = asel[nofs + 48];
        const uint4 n4 = asel[nofs + 64],  n5 = asel[nofs + 80];
        const uint4 n6 = asel[nofs + 96],  n7 = asel[nofs + 112];

        unsigned int m = 0u;
        __builtin_amdgcn_s_setprio(1);
        KSTEP(c0) KSTEP(c1) KSTEP(c2) KSTEP(c3)
        KSTEP(c4) KSTEP(c5) KSTEP(c6) KSTEP(c7)
        __builtin_amdgcn_s_setprio(0);

        // decode this stage's 32 bits; exact f32 rescore from pts (L2)
        const int base = s * SCOLS + wv * 128;
        while (m) {
            const int b = __ffs(m) - 1;
            m &= m - 1;
            const int t = 31 - b;                 // t = mt*4 + r
            const int col = base + (t >> 2) * 16 + g * 4 + (t & 3);
            const float4 q = pts[col];
            const float d2 = fmaxf(fmaf(ax, q.x, fmaf(ay, q.y, fmaf(az, q.z, sq + q.w))), 0.0f);
            unsigned int key = (__float_as_uint(d2) & 0xFFFFE000u) | (unsigned int)col;
            key = (col == arow) ? ~0u : key;      // drop self
            insert8(best, key);
        }

        c0 = n0; c1 = n1; c2 = n2; c3 = n3;
        c4 = n4; c5 = n5; c6 = n6; c7 = n7;
    }
#undef KSTEP

    // merge the 4 g-lanes sharing this row within the wave
#pragma unroll
    for (int st = 16; st <= 32; st <<= 1) {
        unsigned int tk[KNN];
#pragma unroll
        for (int s = 0; s < KNN; ++s) tk[s] = __shfl_xor(best[s], st);
#pragma unroll
        for (int s = 0; s < KNN; ++s) insert8(best, tk[s]);
    }
    // merge across 8 waves (LDS tree)
    if (l < RPB) {
#pragma unroll
        for (int s = 0; s < KNN; ++s) km[wv][l][s] = best[s];
    }
    for (int st = 1; st < 8; st <<= 1) {
        __syncthreads();
        if (((wv & (2 * st - 1)) == 0) && l < RPB) {
#pragma unroll
            for (int s = 0; s < KNN; ++s) insert8(best, km[wv + st][l][s]);
#pragma unroll
            for (int s = 0; s < KNN; ++s) km[wv][l][s] = best[s];
        }
    }

    // finalize: wave 0, lanes 0..15 hold the 16 rows
    if (wv == 0) {
        float sum = 0.0f;
        if (l < RPB) {
            const float nx = normals[3 * arow + 0];
            const float ny = normals[3 * arow + 1];
            const float nz = normals[3 * arow + 2];
#pragma unroll
            for (int s = 0; s < KNN; ++s) {
                const int nbr = (int)(best[s] & 0x1FFFu);
                const float4 q = pts[nbr];
                sum += fabsf((q.x - mp.x) * nx + (q.y - mp.y) * ny + (q.z - mp.z) * nz);
            }
        }
#pragma unroll
        for (int off = 8; off > 0; off >>= 1) sum += __shfl_down(sum, off);
        if (l == 0) atomicAdd(out, sum * (1.0f / ((float)NPTS * (float)KNN)));
    }
}

extern "C" void kernel_launch(void* const* d_in, const int* in_sizes, int n_in,
                              void* d_out, int out_size, void* d_ws, size_t ws_size,
                              hipStream_t stream) {
    const float* means = (const float*)d_in[0];
    const float* normals = (const float*)d_in[1];
    float* out = (float*)d_out;
    char* ws = (char*)d_ws;
    uint4* cf0 = (uint4*)ws;                        // 128 KB
    uint4* cf1 = (uint4*)(ws + 131072);             // 128 KB
    uint4* rf0 = (uint4*)(ws + 262144);             // 128 KB
    uint4* rf1 = (uint4*)(ws + 393216);             // 128 KB
    float4* pts = (float4*)(ws + 524288);           // 128 KB
    float* Tm = (float*)(ws + 655360);              // 32 KB

    prep_thresh<<<NPTS / 32, 512, 0, stream>>>(means, pts, cf0, cf1, rf0, rf1, Tm, out);
    mfma_knn<<<NPTS / RPB, 512, 0, stream>>>(cf0, cf1, rf0, rf1, pts, Tm, normals, out);
}